// Round 1
// baseline (980.879 us; speedup 1.0000x reference)
//
#include <hip/hip_runtime.h>
#include <math.h>

#define N_NODES 20000
#define E_EDGES 640000

// ---------------- CSR build ----------------

__global__ void count_kernel(const int* __restrict__ dst, int* __restrict__ counts) {
    int e = blockIdx.x * blockDim.x + threadIdx.x;
    if (e < E_EDGES) atomicAdd(&counts[dst[e]], 1);
}

__global__ __launch_bounds__(1024) void scan_kernel(const int* __restrict__ counts,
                                                    int* __restrict__ offsets,
                                                    int* __restrict__ cursor) {
    __shared__ int part[1024];
    const int tid = threadIdx.x;
    const int CHUNK = (N_NODES + 1023) / 1024;  // 20
    int start = tid * CHUNK;
    int end = start + CHUNK;
    if (start > N_NODES) start = N_NODES;
    if (end > N_NODES) end = N_NODES;
    int sum = 0;
    for (int i = start; i < end; ++i) sum += counts[i];
    part[tid] = sum;
    __syncthreads();
    // Hillis-Steele inclusive scan over 1024 partials
    for (int off = 1; off < 1024; off <<= 1) {
        int v = 0;
        if (tid >= off) v = part[tid - off];
        __syncthreads();
        if (tid >= off) part[tid] += v;
        __syncthreads();
    }
    int running = (tid == 0) ? 0 : part[tid - 1];
    for (int i = start; i < end; ++i) {
        offsets[i] = running;
        cursor[i]  = running;
        running += counts[i];
    }
    if (end == N_NODES && start < N_NODES) offsets[N_NODES] = running;  // == E
}

__global__ void scatter_kernel(const int* __restrict__ dst, int* __restrict__ cursor,
                               int* __restrict__ edge_list) {
    int e = blockIdx.x * blockDim.x + threadIdx.x;
    if (e < E_EDGES) {
        int pos = atomicAdd(&cursor[dst[e]], 1);
        edge_list[pos] = e;
    }
}

// ---------------- fused attention: one wave per node, online softmax ----------------
//
// q concat layout: q_flat[128] with index i = ch*4 + dd; dd==0 -> query_0[n,ch],
// dd in 1..3 -> query_1[n,ch,dd-1]. Head h = i/16 -> lanes [8h, 8h+8).
// Lane l owns key features 2l,2l+1 and value channel l (v[e, l*3 .. l*3+2]).
__global__ __launch_bounds__(64) void attn_kernel(
    const float* __restrict__ value,     // (E, 64, 3)
    const float* __restrict__ key_feat,  // (E, 128)
    const float* __restrict__ query_0,   // (N, 32)
    const float* __restrict__ query_1,   // (N, 32, 3)
    const int* __restrict__ offsets,     // (N+1)
    const int* __restrict__ edge_list,   // (E)
    float* __restrict__ out0,            // (N, 32)      = feat[:, :32, 0]
    float* __restrict__ out1,            // (N, 32, 3)   = feat[:, 32:, :]
    float* __restrict__ prelog)          // (E, 8)
{
    const int n    = blockIdx.x;
    const int lane = threadIdx.x;
    const int ch   = lane >> 1;
    const int head = lane >> 3;

    float qx, qy;
    if ((lane & 1) == 0) {
        qx = query_0[n * 32 + ch];
        qy = query_1[(n * 32 + ch) * 3 + 0];
    } else {
        qx = query_1[(n * 32 + ch) * 3 + 1];
        qy = query_1[(n * 32 + ch) * 3 + 2];
    }

    const int base = offsets[n];
    const int deg  = offsets[n + 1] - base;

    float m = -INFINITY, lsum = 0.f;
    float a0 = 0.f, a1 = 0.f, a2 = 0.f;

    for (int t = 0; t < deg; ++t) {
        const int e = edge_list[base + t];
        const float2 kf = *reinterpret_cast<const float2*>(key_feat + (size_t)e * 128 + 2 * lane);
        float part = kf.x * qx + kf.y * qy;
        // reduce over the 8-lane head group (xor 1,2,4); all 8 lanes end with the head logit
        part += __shfl_xor(part, 1);
        part += __shfl_xor(part, 2);
        part += __shfl_xor(part, 4);
        const float pre = part * 0.08838834764831845f;  // 1/sqrt(128)
        if ((lane & 7) == 0) prelog[(size_t)e * 8 + head] = pre;

        const float mnew  = fmaxf(m, pre);
        const float scale = __expf(m - mnew);   // first iter: exp(-inf) = 0
        const float p     = __expf(pre - mnew);
        lsum = lsum * scale + p;

        const float* vp = value + (size_t)e * 192 + 3 * lane;
        a0 = a0 * scale + p * vp[0];
        a1 = a1 * scale + p * vp[1];
        a2 = a2 * scale + p * vp[2];
        m = mnew;
    }

    const float inv = (lsum > 0.f) ? 1.0f / lsum : 0.f;  // deg==0 -> feat = 0
    a0 *= inv; a1 *= inv; a2 *= inv;

    if (lane < 32) {
        out0[n * 32 + lane] = a0;            // channels 0..31, d=0
    } else {
        const int c = lane - 32;             // channels 32..63, d=0..2
        float* p1 = out1 + ((size_t)n * 32 + c) * 3;
        p1[0] = a0; p1[1] = a1; p1[2] = a2;
    }
}

// ---------------- launch ----------------

extern "C" void kernel_launch(void* const* d_in, const int* in_sizes, int n_in,
                              void* d_out, int out_size, void* d_ws, size_t ws_size,
                              hipStream_t stream) {
    const float* value    = (const float*)d_in[0];
    const float* key_feat = (const float*)d_in[1];
    const float* query_0  = (const float*)d_in[2];
    const float* query_1  = (const float*)d_in[3];
    const int*   dst      = (const int*)d_in[4];

    float* out    = (float*)d_out;
    float* out0   = out;                    // N*32
    float* out1   = out + N_NODES * 32;     // N*96
    float* prelog = out + N_NODES * 128;    // E*8

    char* ws = (char*)d_ws;
    int* counts    = (int*)(ws + 0);         // N ints
    int* offsets   = (int*)(ws + (1 << 17)); // N+1 ints
    int* cursor    = (int*)(ws + (2 << 17)); // N ints
    int* edge_list = (int*)(ws + (3 << 17)); // E ints  (total ~2.95 MB)

    hipMemsetAsync(counts, 0, N_NODES * sizeof(int), stream);

    const int EB = 256, EG = (E_EDGES + EB - 1) / EB;
    count_kernel<<<EG, EB, 0, stream>>>(dst, counts);
    scan_kernel<<<1, 1024, 0, stream>>>(counts, offsets, cursor);
    scatter_kernel<<<EG, EB, 0, stream>>>(dst, cursor, edge_list);
    attn_kernel<<<N_NODES, 64, 0, stream>>>(value, key_feat, query_0, query_1,
                                            offsets, edge_list, out0, out1, prelog);
}